// Round 1
// baseline (52.334 us; speedup 1.0000x reference)
//
#include <hip/hip_runtime.h>
#include <math.h>

constexpr int TLEN = 512;
constexpr int CDIM = 64;
constexpr int BDIM = 2;

// Phase 1: hk[b,t,c] = sum_d x1[b,t,d]*W1[c,d]; hq: W1[c,128+d]; v[b,t,h]=sum_c x*Wv[h,c]
__global__ __launch_bounds__(256) void phase1_kernel(
    const float* __restrict__ x, const float* __restrict__ pos,
    const float* __restrict__ W1, const float* __restrict__ Wv,
    float* __restrict__ hk, float* __restrict__ hq, float* __restrict__ v)
{
    const int tid = threadIdx.x;
    const int c   = tid & 63;
    const int sub = tid >> 6;                 // 4 rows per block
    const int row = blockIdx.x * 4 + sub;     // b*TLEN + t
    const int t   = row & (TLEN - 1);

    __shared__ float x1s[4][128];
    x1s[sub][c]        = pos[t * CDIM + c];
    x1s[sub][CDIM + c] = x[row * CDIM + c];
    __syncthreads();

    const float* w1row = W1 + c * 256;
    float hk_acc = 0.f, hq_acc = 0.f;
    #pragma unroll 8
    for (int d = 0; d < 128; ++d) {
        const float xv = x1s[sub][d];
        hk_acc = fmaf(xv, w1row[d], hk_acc);
        hq_acc = fmaf(xv, w1row[128 + d], hq_acc);
    }
    float v_acc = 0.f;
    const float* wvrow = Wv + c * CDIM;       // c plays the role of h here
    #pragma unroll 8
    for (int d = 0; d < 64; ++d)
        v_acc = fmaf(x1s[sub][CDIM + d], wvrow[d], v_acc);

    hk[row * CDIM + c] = hk_acc;
    hq[row * CDIM + c] = hq_acc;
    v[row * CDIM + c]  = v_acc;
}

// Phase 2: one block per output row (b,i). scores -> softmax -> PV.
__global__ __launch_bounds__(256) void phase2_kernel(
    const float* __restrict__ hk, const float* __restrict__ hq,
    const float* __restrict__ v,  const float* __restrict__ b1,
    const float* __restrict__ W2, const float* __restrict__ b2,
    float* __restrict__ out)
{
    const int tid = threadIdx.x;
    const int row = blockIdx.x;               // b*TLEN + i
    const int b   = row >> 9;
    const int i   = row & (TLEN - 1);

    __shared__ float hq_s[CDIM];              // hq + b1 folded
    __shared__ float w2_s[CDIM];
    __shared__ float p_s[TLEN];
    __shared__ float red_s[4];
    __shared__ float pv_s[4][CDIM];

    if (tid < CDIM) {
        hq_s[tid] = hq[row * CDIM + tid] + b1[tid];
        w2_s[tid] = W2[tid];
    }
    __syncthreads();

    const float b2v = b2[0];
    float sc[2];
    float m_local = -1e30f;
    #pragma unroll
    for (int k = 0; k < 2; ++k) {
        const int j = tid + k * 256;
        float s = -1e30f;
        if (j <= i) {
            const float* hkr = hk + (b * TLEN + j) * CDIM;
            float acc = 0.f;
            #pragma unroll 8
            for (int c = 0; c < CDIM; ++c)
                acc = fmaf(fmaxf(hq_s[c] + hkr[c], 0.f), w2_s[c], acc);
            s = (acc + b2v) * 0.125f;         // * C^-0.5
        }
        sc[k] = s;
        m_local = fmaxf(m_local, s);
    }
    // block max: wave shfl reduce, then 4-wave LDS combine
    #pragma unroll
    for (int off = 32; off > 0; off >>= 1)
        m_local = fmaxf(m_local, __shfl_xor(m_local, off));
    const int wid = tid >> 6;
    if ((tid & 63) == 0) red_s[wid] = m_local;
    __syncthreads();
    const float m = fmaxf(fmaxf(red_s[0], red_s[1]), fmaxf(red_s[2], red_s[3]));

    float sum_local = 0.f;
    #pragma unroll
    for (int k = 0; k < 2; ++k) {
        const int j = tid + k * 256;
        const float p = (j <= i) ? __expf(sc[k] - m) : 0.f;
        p_s[j] = p;                            // j < 512 always
        sum_local += p;
    }
    #pragma unroll
    for (int off = 32; off > 0; off >>= 1)
        sum_local += __shfl_xor(sum_local, off);
    __syncthreads();                           // red_s (max) fully read; p_s visible
    if ((tid & 63) == 0) red_s[wid] = sum_local;
    __syncthreads();
    const float inv = 1.f / (red_s[0] + red_s[1] + red_s[2] + red_s[3]);

    // PV: wave-coalesced over h; 4 j-groups reduced via LDS
    const int h = tid & 63;
    const int g = tid >> 6;
    float acc = 0.f;
    for (int j = g; j <= i; j += 4)
        acc = fmaf(p_s[j], v[(b * TLEN + j) * CDIM + h], acc);
    pv_s[g][h] = acc;
    __syncthreads();
    if (tid < CDIM)
        out[row * CDIM + tid] =
            (pv_s[0][tid] + pv_s[1][tid] + pv_s[2][tid] + pv_s[3][tid]) * inv;
}

extern "C" void kernel_launch(void* const* d_in, const int* in_sizes, int n_in,
                              void* d_out, int out_size, void* d_ws, size_t ws_size,
                              hipStream_t stream)
{
    const float* x   = (const float*)d_in[0];
    const float* pos = (const float*)d_in[1];
    const float* W1  = (const float*)d_in[2];
    const float* b1  = (const float*)d_in[3];
    const float* W2  = (const float*)d_in[4];
    const float* b2  = (const float*)d_in[5];
    const float* Wv  = (const float*)d_in[6];
    float* out = (float*)d_out;

    float* hk = (float*)d_ws;                 // 3 x 256 KiB in workspace
    float* hq = hk + BDIM * TLEN * CDIM;
    float* v  = hq + BDIM * TLEN * CDIM;

    phase1_kernel<<<BDIM * TLEN / 4, 256, 0, stream>>>(x, pos, W1, Wv, hk, hq, v);
    phase2_kernel<<<BDIM * TLEN, 256, 0, stream>>>(hk, hq, v, b1, W2, b2, out);
}

// Round 2
// 32.583 us; speedup vs baseline: 1.6062x; 1.6062x over previous
//
#include <hip/hip_runtime.h>
#include <math.h>

constexpr int TLEN = 512;
constexpr int CDIM = 64;
constexpr int BDIM = 2;

// Phase 1: hk[b,t,c] = sum_d x1[b,t,d]*W1[c,d]; hq: W1[c,128+d]; v[b,t,h]=sum_c x[b,t,c]*Wv[h,c]
__global__ __launch_bounds__(256) void phase1_kernel(
    const float* __restrict__ x, const float* __restrict__ pos,
    const float* __restrict__ W1, const float* __restrict__ Wv,
    float* __restrict__ hk, float* __restrict__ hq, float* __restrict__ v)
{
    const int tid = threadIdx.x;
    const int c   = tid & 63;
    const int sub = tid >> 6;                 // 4 rows per block
    const int row = blockIdx.x * 4 + sub;     // b*TLEN + t
    const int t   = row & (TLEN - 1);

    __shared__ alignas(16) float x1s[4][128];
    x1s[sub][c]        = pos[t * CDIM + c];
    x1s[sub][CDIM + c] = x[row * CDIM + c];
    __syncthreads();

    const float4* w1k = (const float4*)(W1 + c * 256);   // 32 float4 (Wk row)
    const float4* w1q = w1k + 32;                        // 32 float4 (Wq row)
    const float4* xv  = (const float4*)x1s[sub];

    float4 ak = make_float4(0.f, 0.f, 0.f, 0.f);
    float4 aq = make_float4(0.f, 0.f, 0.f, 0.f);
    #pragma unroll
    for (int d4 = 0; d4 < 32; ++d4) {
        const float4 xx = xv[d4];
        const float4 wk = w1k[d4];
        const float4 wq = w1q[d4];
        ak.x = fmaf(xx.x, wk.x, ak.x); ak.y = fmaf(xx.y, wk.y, ak.y);
        ak.z = fmaf(xx.z, wk.z, ak.z); ak.w = fmaf(xx.w, wk.w, ak.w);
        aq.x = fmaf(xx.x, wq.x, aq.x); aq.y = fmaf(xx.y, wq.y, aq.y);
        aq.z = fmaf(xx.z, wq.z, aq.z); aq.w = fmaf(xx.w, wq.w, aq.w);
    }

    const float4* wvr = (const float4*)(Wv + c * CDIM);  // 16 float4 (c == h role)
    const float4* xv2 = xv + 16;                          // x part of x1
    float4 av = make_float4(0.f, 0.f, 0.f, 0.f);
    #pragma unroll
    for (int d4 = 0; d4 < 16; ++d4) {
        const float4 xx = xv2[d4];
        const float4 wv = wvr[d4];
        av.x = fmaf(xx.x, wv.x, av.x); av.y = fmaf(xx.y, wv.y, av.y);
        av.z = fmaf(xx.z, wv.z, av.z); av.w = fmaf(xx.w, wv.w, av.w);
    }

    hk[row * CDIM + c] = (ak.x + ak.y) + (ak.z + ak.w);
    hq[row * CDIM + c] = (aq.x + aq.y) + (aq.z + aq.w);
    v[row * CDIM + c]  = (av.x + av.y) + (av.z + av.w);
}

// Phase 2: one block per output row (b,i), heaviest rows dispatched first.
__global__ __launch_bounds__(256) void phase2_kernel(
    const float* __restrict__ hk, const float* __restrict__ hq,
    const float* __restrict__ v,  const float* __restrict__ b1,
    const float* __restrict__ W2, const float* __restrict__ b2,
    float* __restrict__ out)
{
    const int tid = threadIdx.x;
    const int idx = blockIdx.x;
    const int i   = (TLEN - 1) - (idx >> 1);  // LPT: big rows first
    const int b   = idx & 1;
    const int row = b * TLEN + i;

    __shared__ float4 hq4_s[16];              // hq + b1 folded
    __shared__ float4 w24_s[16];
    __shared__ float p_s[TLEN];
    __shared__ float red_s[4];
    __shared__ float pv_s[4][CDIM];

    if (tid < 16) {
        const float4 h  = ((const float4*)(hq + row * CDIM))[tid];
        const float4 bb = ((const float4*)b1)[tid];
        hq4_s[tid] = make_float4(h.x + bb.x, h.y + bb.y, h.z + bb.z, h.w + bb.w);
        w24_s[tid] = ((const float4*)W2)[tid];
    }
    __syncthreads();

    const float b2v = b2[0];
    float sc[2];
    float m_local = -1e30f;
    #pragma unroll
    for (int k = 0; k < 2; ++k) {
        const int j = tid + k * 256;
        float s = -1e30f;
        if (j <= i) {
            const float4* hk4 = (const float4*)(hk + (b * TLEN + j) * CDIM);
            float4 acc = make_float4(0.f, 0.f, 0.f, 0.f);
            #pragma unroll
            for (int c4 = 0; c4 < 16; ++c4) {
                const float4 kk = hk4[c4];
                const float4 qq = hq4_s[c4];
                const float4 ww = w24_s[c4];
                acc.x = fmaf(fmaxf(qq.x + kk.x, 0.f), ww.x, acc.x);
                acc.y = fmaf(fmaxf(qq.y + kk.y, 0.f), ww.y, acc.y);
                acc.z = fmaf(fmaxf(qq.z + kk.z, 0.f), ww.z, acc.z);
                acc.w = fmaf(fmaxf(qq.w + kk.w, 0.f), ww.w, acc.w);
            }
            s = ((acc.x + acc.y) + (acc.z + acc.w) + b2v) * 0.125f;
        }
        sc[k] = s;
        m_local = fmaxf(m_local, s);
    }
    // block max: wave shfl reduce, then 4-wave LDS combine
    #pragma unroll
    for (int off = 32; off > 0; off >>= 1)
        m_local = fmaxf(m_local, __shfl_xor(m_local, off));
    const int wid = tid >> 6;
    if ((tid & 63) == 0) red_s[wid] = m_local;
    __syncthreads();
    const float m = fmaxf(fmaxf(red_s[0], red_s[1]), fmaxf(red_s[2], red_s[3]));

    float sum_local = 0.f;
    #pragma unroll
    for (int k = 0; k < 2; ++k) {
        const int j = tid + k * 256;
        const float p = (j <= i) ? __expf(sc[k] - m) : 0.f;
        p_s[j] = p;
        sum_local += p;
    }
    #pragma unroll
    for (int off = 32; off > 0; off >>= 1)
        sum_local += __shfl_xor(sum_local, off);
    __syncthreads();                           // max fully consumed; p_s visible
    if ((tid & 63) == 0) red_s[wid] = sum_local;
    __syncthreads();
    const float inv = 1.f / (red_s[0] + red_s[1] + red_s[2] + red_s[3]);

    // PV: wave-coalesced over h; 4 j-groups reduced via LDS
    const int h = tid & 63;
    const int g = tid >> 6;
    float acc = 0.f;
    #pragma unroll 4
    for (int j = g; j <= i; j += 4)
        acc = fmaf(p_s[j], v[(b * TLEN + j) * CDIM + h], acc);
    pv_s[g][h] = acc;
    __syncthreads();
    if (tid < CDIM)
        out[row * CDIM + tid] =
            (pv_s[0][tid] + pv_s[1][tid] + pv_s[2][tid] + pv_s[3][tid]) * inv;
}

extern "C" void kernel_launch(void* const* d_in, const int* in_sizes, int n_in,
                              void* d_out, int out_size, void* d_ws, size_t ws_size,
                              hipStream_t stream)
{
    const float* x   = (const float*)d_in[0];
    const float* pos = (const float*)d_in[1];
    const float* W1  = (const float*)d_in[2];
    const float* b1  = (const float*)d_in[3];
    const float* W2  = (const float*)d_in[4];
    const float* b2  = (const float*)d_in[5];
    const float* Wv  = (const float*)d_in[6];
    float* out = (float*)d_out;

    float* hk = (float*)d_ws;                 // 3 x 256 KiB in workspace
    float* hq = hk + BDIM * TLEN * CDIM;
    float* v  = hq + BDIM * TLEN * CDIM;

    phase1_kernel<<<BDIM * TLEN / 4, 256, 0, stream>>>(x, pos, W1, Wv, hk, hq, v);
    phase2_kernel<<<BDIM * TLEN, 256, 0, stream>>>(hk, hq, v, b1, W2, b2, out);
}

// Round 4
// 30.118 us; speedup vs baseline: 1.7376x; 1.0819x over previous
//
#include <hip/hip_runtime.h>
#include <math.h>

constexpr int TLEN = 512;
constexpr int CDIM = 64;
constexpr int BDIM = 2;

// Phase 1: hk[b,t,c] = sum_d x1[b,t,d]*W1[c,d]; hq: W1[c,128+d]; v[b,t,h]=sum_c x[b,t,c]*Wv[h,c]
__global__ __launch_bounds__(256) void phase1_kernel(
    const float* __restrict__ x, const float* __restrict__ pos,
    const float* __restrict__ W1, const float* __restrict__ Wv,
    const float* __restrict__ b1,
    float* __restrict__ hk, float* __restrict__ hq, float* __restrict__ v)
{
    const int tid = threadIdx.x;
    const int c   = tid & 63;
    const int sub = tid >> 6;                 // 4 rows per block
    const int row = blockIdx.x * 4 + sub;     // b*TLEN + t
    const int t   = row & (TLEN - 1);

    __shared__ alignas(16) float x1s[4][128];
    x1s[sub][c]        = pos[t * CDIM + c];
    x1s[sub][CDIM + c] = x[row * CDIM + c];
    __syncthreads();

    const float4* w1k = (const float4*)(W1 + c * 256);   // 32 float4 (Wk row)
    const float4* w1q = w1k + 32;                        // 32 float4 (Wq row)
    const float4* xv  = (const float4*)x1s[sub];

    float4 ak = make_float4(0.f, 0.f, 0.f, 0.f);
    float4 aq = make_float4(0.f, 0.f, 0.f, 0.f);
    #pragma unroll
    for (int d4 = 0; d4 < 32; ++d4) {
        const float4 xx = xv[d4];
        const float4 wk = w1k[d4];
        const float4 wq = w1q[d4];
        ak.x = fmaf(xx.x, wk.x, ak.x); ak.y = fmaf(xx.y, wk.y, ak.y);
        ak.z = fmaf(xx.z, wk.z, ak.z); ak.w = fmaf(xx.w, wk.w, ak.w);
        aq.x = fmaf(xx.x, wq.x, aq.x); aq.y = fmaf(xx.y, wq.y, aq.y);
        aq.z = fmaf(xx.z, wq.z, aq.z); aq.w = fmaf(xx.w, wq.w, aq.w);
    }

    const float4* wvr = (const float4*)(Wv + c * CDIM);  // 16 float4 (c == h role)
    const float4* xv2 = xv + 16;                          // x part of x1
    float4 av = make_float4(0.f, 0.f, 0.f, 0.f);
    #pragma unroll
    for (int d4 = 0; d4 < 16; ++d4) {
        const float4 xx = xv2[d4];
        const float4 wv = wvr[d4];
        av.x = fmaf(xx.x, wv.x, av.x); av.y = fmaf(xx.y, wv.y, av.y);
        av.z = fmaf(xx.z, wv.z, av.z); av.w = fmaf(xx.w, wv.w, av.w);
    }

    hk[row * CDIM + c] = (ak.x + ak.y) + (ak.z + ak.w);
    hq[row * CDIM + c] = (aq.x + aq.y) + (aq.z + aq.w) + b1[c];  // b1 folded here
    v[row * CDIM + c]  = (av.x + av.y) + (av.z + av.w);
}

// Phase 2: one block per row-PAIR (iA, 511-iA) of one batch: exactly 513
// score-columns per block -> perfect static balance. 512 threads: thread j
// computes score column j (one per row). PV via float4 p reads + 8 j-groups.
__global__ __launch_bounds__(512) void phase2_kernel(
    const float* __restrict__ hk, const float* __restrict__ hq,
    const float* __restrict__ v,  const float* __restrict__ W2,
    const float* __restrict__ b2, float* __restrict__ out)
{
    const int tid = threadIdx.x;
    const int idx = blockIdx.x;               // 0..511
    const int b   = idx & 1;
    const int iA  = idx >> 1;                 // 0..255
    const int iB  = (TLEN - 1) - iA;          // 256..511

    __shared__ float4 hq4_s[2][16];           // hq (+b1 already folded)
    __shared__ float4 w24_s[16];
    __shared__ alignas(16) float p_s[TLEN];
    __shared__ float red_s[8];
    __shared__ float pv_s[8][CDIM];

    if (tid < 32) {
        const int rp = tid >> 4, e = tid & 15;
        const int row = b * TLEN + (rp ? iB : iA);
        hq4_s[rp][e] = ((const float4*)(hq + row * CDIM))[e];
    } else if (tid < 48) {
        w24_s[tid - 32] = ((const float4*)W2)[tid - 32];
    }
    __syncthreads();

    const float b2v = b2[0];
    const float* hkb = hk + b * TLEN * CDIM;
    const int wid = tid >> 6;

    #pragma unroll
    for (int rp = 0; rp < 2; ++rp) {
        const int i   = rp ? iB : iA;
        const int row = b * TLEN + i;
        const int j   = tid;

        float s = -1e30f;
        if (j <= i) {
            const float4* hk4 = (const float4*)(hkb + j * CDIM);
            float4 acc = make_float4(0.f, 0.f, 0.f, 0.f);
            #pragma unroll
            for (int c4 = 0; c4 < 16; ++c4) {
                const float4 kk = hk4[c4];
                const float4 qq = hq4_s[rp][c4];
                const float4 ww = w24_s[c4];
                acc.x = fmaf(fmaxf(qq.x + kk.x, 0.f), ww.x, acc.x);
                acc.y = fmaf(fmaxf(qq.y + kk.y, 0.f), ww.y, acc.y);
                acc.z = fmaf(fmaxf(qq.z + kk.z, 0.f), ww.z, acc.z);
                acc.w = fmaf(fmaxf(qq.w + kk.w, 0.f), ww.w, acc.w);
            }
            s = ((acc.x + acc.y) + (acc.z + acc.w) + b2v) * 0.125f;
        }

        // block max: wave shfl reduce, then 8-wave LDS combine
        float m_local = s;
        #pragma unroll
        for (int off = 32; off > 0; off >>= 1)
            m_local = fmaxf(m_local, __shfl_xor(m_local, off));
        if ((tid & 63) == 0) red_s[wid] = m_local;
        __syncthreads();
        float m = red_s[0];
        #pragma unroll
        for (int w = 1; w < 8; ++w) m = fmaxf(m, red_s[w]);

        const float p = (j <= i) ? __expf(s - m) : 0.f;
        p_s[j] = p;
        float sum_local = p;
        #pragma unroll
        for (int off = 32; off > 0; off >>= 1)
            sum_local += __shfl_xor(sum_local, off);
        __syncthreads();                       // max consumed; p_s visible
        if ((tid & 63) == 0) red_s[wid] = sum_local;
        __syncthreads();
        float sum = red_s[0];
        #pragma unroll
        for (int w = 1; w < 8; ++w) sum += red_s[w];
        const float inv = 1.f / sum;

        // PV: 8 j-groups; per iter: 1 ds_read_b128 of p + 4 coalesced v rows
        const int h = tid & 63;
        const int g = wid;
        const float* vb = v + b * TLEN * CDIM + h;
        const float4* p4 = (const float4*)p_s;
        const int nj4 = (i >> 2) + 1;          // float4 groups covering j<=i
        float a0 = 0.f, a1 = 0.f, a2 = 0.f, a3 = 0.f;
        for (int j4 = g; j4 < nj4; j4 += 8) {
            const float4 pp = p4[j4];
            const int j0 = j4 * 4;
            a0 = fmaf(pp.x, vb[j0 * CDIM],       a0);
            a1 = fmaf(pp.y, vb[(j0 + 1) * CDIM], a1);
            a2 = fmaf(pp.z, vb[(j0 + 2) * CDIM], a2);
            a3 = fmaf(pp.w, vb[(j0 + 3) * CDIM], a3);
        }
        pv_s[g][h] = (a0 + a1) + (a2 + a3);
        __syncthreads();
        if (tid < CDIM) {
            float o = pv_s[0][tid];
            #pragma unroll
            for (int w = 1; w < 8; ++w) o += pv_s[w][tid];
            out[row * CDIM + tid] = o * inv;
        }
        __syncthreads();                       // protect p_s/red_s/pv_s for rp=1
    }
}

extern "C" void kernel_launch(void* const* d_in, const int* in_sizes, int n_in,
                              void* d_out, int out_size, void* d_ws, size_t ws_size,
                              hipStream_t stream)
{
    const float* x   = (const float*)d_in[0];
    const float* pos = (const float*)d_in[1];
    const float* W1  = (const float*)d_in[2];
    const float* b1  = (const float*)d_in[3];
    const float* W2  = (const float*)d_in[4];
    const float* b2  = (const float*)d_in[5];
    const float* Wv  = (const float*)d_in[6];
    float* out = (float*)d_out;

    float* hk = (float*)d_ws;                 // 3 x 256 KiB in workspace
    float* hq = hk + BDIM * TLEN * CDIM;
    float* v  = hq + BDIM * TLEN * CDIM;

    phase1_kernel<<<BDIM * TLEN / 4, 256, 0, stream>>>(x, pos, W1, Wv, b1, hk, hq, v);
    phase2_kernel<<<BDIM * TLEN / 2, 512, 0, stream>>>(hk, hq, v, W2, b2, out);
}

// Round 5
// 29.585 us; speedup vs baseline: 1.7690x; 1.0180x over previous
//
#include <hip/hip_runtime.h>
#include <math.h>

constexpr int TLEN = 512;
constexpr int CDIM = 64;
constexpr int BDIM = 2;

// Phase 1: hk[b,t,c] = sum_d x1[b,t,d] * W1[c,d]   (Wk = W1[:, :128])
// Bounded unroll: no register-pressure blowup.
__global__ __launch_bounds__(256) void hk_kernel(
    const float* __restrict__ x, const float* __restrict__ pos,
    const float* __restrict__ W1, float* __restrict__ hk)
{
    const int tid = threadIdx.x;
    const int c   = tid & 63;
    const int sub = tid >> 6;                 // 4 rows per block
    const int row = blockIdx.x * 4 + sub;     // b*TLEN + t

    __shared__ alignas(16) float x1s[4][128];
    #pragma unroll
    for (int e = tid; e < 4 * 128; e += 256) {
        const int r4 = e >> 7, d = e & 127;
        const int rr = blockIdx.x * 4 + r4;
        const int tt = rr & (TLEN - 1);
        x1s[r4][d] = (d < CDIM) ? pos[tt * CDIM + d] : x[rr * CDIM + (d - CDIM)];
    }
    __syncthreads();

    const float4* wk = (const float4*)(W1 + c * 256);    // row c, cols 0..127
    const float4* xv = (const float4*)x1s[sub];
    float4 a = make_float4(0.f, 0.f, 0.f, 0.f);
    #pragma unroll 8
    for (int d4 = 0; d4 < 32; ++d4) {
        const float4 xx = xv[d4];
        const float4 ww = wk[d4];
        a.x = fmaf(xx.x, ww.x, a.x); a.y = fmaf(xx.y, ww.y, a.y);
        a.z = fmaf(xx.z, ww.z, a.z); a.w = fmaf(xx.w, ww.w, a.w);
    }
    hk[row * CDIM + c] = (a.x + a.y) + (a.z + a.w);
}

// Phase 2: one block per row-pair (iA, 511-iA) of one batch (513 score
// columns -> perfectly balanced). Computes hq locally, scores, softmax,
// o = sum_j p_j * x_j, then out = (o @ Wv^T) * inv.
__global__ __launch_bounds__(512) void attn_kernel(
    const float* __restrict__ x,  const float* __restrict__ pos,
    const float* __restrict__ W1, const float* __restrict__ b1,
    const float* __restrict__ W2, const float* __restrict__ b2,
    const float* __restrict__ Wv, const float* __restrict__ hk,
    float* __restrict__ out)
{
    const int tid = threadIdx.x;
    const int idx = blockIdx.x;               // 0..511
    const int b   = idx & 1;
    const int iA  = idx >> 1;                 // 0..255
    const int iB  = (TLEN - 1) - iA;          // 256..511

    __shared__ alignas(16) float x1s[2][128];
    __shared__ alignas(16) float hq_s[2][CDIM];
    __shared__ float hqp[2][CDIM][4];         // hq partials (4-way d split)
    __shared__ float4 w2_s[16];
    __shared__ alignas(16) float p_s[TLEN];
    __shared__ float red_s[8];
    __shared__ float pv_s[8][CDIM];
    __shared__ alignas(16) float o_s[CDIM];

    // stage x1 for both rows + W2
    if (tid < 256) {
        const int rp = tid >> 7, d = tid & 127;
        const int i  = rp ? iB : iA;
        const int r  = b * TLEN + i;
        x1s[rp][d] = (d < CDIM) ? pos[i * CDIM + d] : x[r * CDIM + (d - CDIM)];
    } else if (tid < 272) {
        w2_s[tid - 256] = ((const float4*)W2)[tid - 256];
    }
    __syncthreads();

    // hq partials: all 512 threads, 8-f4 chains (short critical path)
    {
        const int rp = tid >> 8, c = (tid >> 2) & 63, part = tid & 3;
        const float4* wq = (const float4*)(W1 + c * 256 + 128) + part * 8;
        const float4* xv = ((const float4*)x1s[rp]) + part * 8;
        float4 a = make_float4(0.f, 0.f, 0.f, 0.f);
        #pragma unroll
        for (int d4 = 0; d4 < 8; ++d4) {
            const float4 xx = xv[d4];
            const float4 ww = wq[d4];
            a.x = fmaf(xx.x, ww.x, a.x); a.y = fmaf(xx.y, ww.y, a.y);
            a.z = fmaf(xx.z, ww.z, a.z); a.w = fmaf(xx.w, ww.w, a.w);
        }
        hqp[rp][c][part] = (a.x + a.y) + (a.z + a.w);
    }
    __syncthreads();
    if (tid < 128) {
        const int rp = tid >> 6, c = tid & 63;
        hq_s[rp][c] = hqp[rp][c][0] + hqp[rp][c][1] + hqp[rp][c][2]
                    + hqp[rp][c][3] + b1[c];
    }
    __syncthreads();

    const float b2v = b2[0];
    const float* hkb = hk + b * TLEN * CDIM;
    const float* xb  = x + b * TLEN * CDIM;
    const int wid = tid >> 6;

    #pragma unroll
    for (int rp = 0; rp < 2; ++rp) {
        const int i   = rp ? iB : iA;
        const int row = b * TLEN + i;
        const int j   = tid;

        float s = -1e30f;
        if (j <= i) {
            const float4* hk4 = (const float4*)(hkb + j * CDIM);
            const float4* hq4 = (const float4*)hq_s[rp];
            float4 acc = make_float4(0.f, 0.f, 0.f, 0.f);
            #pragma unroll
            for (int c4 = 0; c4 < 16; ++c4) {
                const float4 kk = hk4[c4];
                const float4 qq = hq4[c4];
                const float4 ww = w2_s[c4];
                acc.x = fmaf(fmaxf(qq.x + kk.x, 0.f), ww.x, acc.x);
                acc.y = fmaf(fmaxf(qq.y + kk.y, 0.f), ww.y, acc.y);
                acc.z = fmaf(fmaxf(qq.z + kk.z, 0.f), ww.z, acc.z);
                acc.w = fmaf(fmaxf(qq.w + kk.w, 0.f), ww.w, acc.w);
            }
            s = ((acc.x + acc.y) + (acc.z + acc.w) + b2v) * 0.125f;
        }

        // block max
        float m_local = s;
        #pragma unroll
        for (int off = 32; off > 0; off >>= 1)
            m_local = fmaxf(m_local, __shfl_xor(m_local, off));
        if ((tid & 63) == 0) red_s[wid] = m_local;
        __syncthreads();
        float m = red_s[0];
        #pragma unroll
        for (int w = 1; w < 8; ++w) m = fmaxf(m, red_s[w]);

        const float p = (j <= i) ? __expf(s - m) : 0.f;
        p_s[j] = p;
        float sum_local = p;
        #pragma unroll
        for (int off = 32; off > 0; off >>= 1)
            sum_local += __shfl_xor(sum_local, off);
        __syncthreads();                       // max consumed; p_s visible
        if ((tid & 63) == 0) red_s[wid] = sum_local;
        __syncthreads();
        float sum = red_s[0];
        #pragma unroll
        for (int w = 1; w < 8; ++w) sum += red_s[w];
        const float inv = 1.f / sum;

        // o = sum_j p_j * x_j  (8 j-groups, float4 p reads, coalesced x rows)
        const int h = tid & 63;
        const int g = wid;
        const float* xh = xb + h;
        const float4* p4 = (const float4*)p_s;
        const int nj4 = (i >> 2) + 1;
        float a0 = 0.f, a1 = 0.f, a2 = 0.f, a3 = 0.f;
        for (int j4 = g; j4 < nj4; j4 += 8) {
            const float4 pp = p4[j4];
            const int j0 = j4 * 4;
            a0 = fmaf(pp.x, xh[j0 * CDIM],       a0);
            a1 = fmaf(pp.y, xh[(j0 + 1) * CDIM], a1);
            a2 = fmaf(pp.z, xh[(j0 + 2) * CDIM], a2);
            a3 = fmaf(pp.w, xh[(j0 + 3) * CDIM], a3);
        }
        pv_s[g][h] = (a0 + a1) + (a2 + a3);
        __syncthreads();
        if (tid < CDIM) {
            float o = pv_s[0][tid];
            #pragma unroll
            for (int w = 1; w < 8; ++w) o += pv_s[w][tid];
            o_s[tid] = o;
        }
        __syncthreads();
        if (tid < CDIM) {                      // out[h] = (o . Wv[h,:]) * inv
            const float4* wv = (const float4*)(Wv + tid * CDIM);
            const float4* o4 = (const float4*)o_s;
            float4 a = make_float4(0.f, 0.f, 0.f, 0.f);
            #pragma unroll
            for (int c4 = 0; c4 < 16; ++c4) {
                const float4 ww = wv[c4];
                const float4 oo = o4[c4];
                a.x = fmaf(oo.x, ww.x, a.x); a.y = fmaf(oo.y, ww.y, a.y);
                a.z = fmaf(oo.z, ww.z, a.z); a.w = fmaf(oo.w, ww.w, a.w);
            }
            out[row * CDIM + tid] = ((a.x + a.y) + (a.z + a.w)) * inv;
        }
        __syncthreads();                       // protect shared bufs for rp=1
    }
}

extern "C" void kernel_launch(void* const* d_in, const int* in_sizes, int n_in,
                              void* d_out, int out_size, void* d_ws, size_t ws_size,
                              hipStream_t stream)
{
    const float* x   = (const float*)d_in[0];
    const float* pos = (const float*)d_in[1];
    const float* W1  = (const float*)d_in[2];
    const float* b1  = (const float*)d_in[3];
    const float* W2  = (const float*)d_in[4];
    const float* b2  = (const float*)d_in[5];
    const float* Wv  = (const float*)d_in[6];
    float* out = (float*)d_out;

    float* hk = (float*)d_ws;                 // 256 KiB scratch

    hk_kernel<<<BDIM * TLEN / 4, 256, 0, stream>>>(x, pos, W1, hk);
    attn_kernel<<<BDIM * TLEN / 2, 512, 0, stream>>>(x, pos, W1, b1, W2, b2, Wv,
                                                     hk, out);
}

// Round 6
// 25.727 us; speedup vs baseline: 2.0342x; 1.1499x over previous
//
#include <hip/hip_runtime.h>
#include <math.h>

constexpr int TLEN = 512;
constexpr int CDIM = 64;
constexpr int BDIM = 2;

// Phase 1: hkt[b][c][t] = sum_d x1[b,t,d] * W1[c,d]  (TRANSPOSED output:
// consumer reads hkt[c*512+j] with lanes over j -> coalesced).
__global__ __launch_bounds__(256) void hk_kernel(
    const float* __restrict__ x, const float* __restrict__ pos,
    const float* __restrict__ W1, float* __restrict__ hkt)
{
    const int tid = threadIdx.x;
    const int c   = tid & 63;
    const int sub = tid >> 6;                 // 4 rows per block
    const int row = blockIdx.x * 4 + sub;     // b*TLEN + t
    const int b   = row >> 9;
    const int t   = row & (TLEN - 1);

    __shared__ alignas(16) float x1s[4][128];
    #pragma unroll
    for (int e = tid; e < 4 * 128; e += 256) {
        const int r4 = e >> 7, d = e & 127;
        const int rr = blockIdx.x * 4 + r4;
        const int tt = rr & (TLEN - 1);
        x1s[r4][d] = (d < CDIM) ? pos[tt * CDIM + d] : x[rr * CDIM + (d - CDIM)];
    }
    __syncthreads();

    const float4* wk = (const float4*)(W1 + c * 256);    // row c, cols 0..127
    const float4* xv = (const float4*)x1s[sub];
    float4 a = make_float4(0.f, 0.f, 0.f, 0.f);
    #pragma unroll 8
    for (int d4 = 0; d4 < 32; ++d4) {
        const float4 xx = xv[d4];
        const float4 ww = wk[d4];
        a.x = fmaf(xx.x, ww.x, a.x); a.y = fmaf(xx.y, ww.y, a.y);
        a.z = fmaf(xx.z, ww.z, a.z); a.w = fmaf(xx.w, ww.w, a.w);
    }
    hkt[(b * CDIM + c) * TLEN + t] = (a.x + a.y) + (a.z + a.w);
}

// Phase 2: one block per row-pair (iA, 511-iA) of one batch (513 score
// columns -> balanced). hq computed locally; scores read hkt coalesced;
// softmax; o = sum_j p_j x_j; out = (o @ Wv^T) * inv.
__global__ __launch_bounds__(512) void attn_kernel(
    const float* __restrict__ x,  const float* __restrict__ pos,
    const float* __restrict__ W1, const float* __restrict__ b1,
    const float* __restrict__ W2, const float* __restrict__ b2,
    const float* __restrict__ Wv, const float* __restrict__ hkt,
    float* __restrict__ out)
{
    const int tid = threadIdx.x;
    const int idx = blockIdx.x;               // 0..511
    const int b   = idx & 1;
    const int iA  = idx >> 1;                 // 0..255
    const int iB  = (TLEN - 1) - iA;          // 256..511

    __shared__ alignas(16) float x1s[2][128];
    __shared__ float hq_s[2][CDIM];
    __shared__ float hqp[2][CDIM][4];         // hq partials (4-way d split)
    __shared__ float w2_s[CDIM];
    __shared__ alignas(16) float p_s[TLEN];
    __shared__ float red_s[8];
    __shared__ float pv_s[8][CDIM];
    __shared__ alignas(16) float o_s[CDIM];

    // stage x1 for both rows + W2
    if (tid < 256) {
        const int rp = tid >> 7, d = tid & 127;
        const int i  = rp ? iB : iA;
        const int r  = b * TLEN + i;
        x1s[rp][d] = (d < CDIM) ? pos[i * CDIM + d] : x[r * CDIM + (d - CDIM)];
    } else if (tid < 320) {
        w2_s[tid - 256] = W2[tid - 256];
    }
    __syncthreads();

    // hq partials: all 512 threads, 8-f4 chains
    {
        const int rp = tid >> 8, c = (tid >> 2) & 63, part = tid & 3;
        const float4* wq = (const float4*)(W1 + c * 256 + 128) + part * 8;
        const float4* xv = ((const float4*)x1s[rp]) + part * 8;
        float4 a = make_float4(0.f, 0.f, 0.f, 0.f);
        #pragma unroll
        for (int d4 = 0; d4 < 8; ++d4) {
            const float4 xx = xv[d4];
            const float4 ww = wq[d4];
            a.x = fmaf(xx.x, ww.x, a.x); a.y = fmaf(xx.y, ww.y, a.y);
            a.z = fmaf(xx.z, ww.z, a.z); a.w = fmaf(xx.w, ww.w, a.w);
        }
        hqp[rp][c][part] = (a.x + a.y) + (a.z + a.w);
    }
    __syncthreads();
    if (tid < 128) {
        const int rp = tid >> 6, c = tid & 63;
        hq_s[rp][c] = hqp[rp][c][0] + hqp[rp][c][1] + hqp[rp][c][2]
                    + hqp[rp][c][3] + b1[c];
    }
    __syncthreads();

    const float b2v = b2[0];
    const float* hkb = hkt + b * CDIM * TLEN; // [c][t]
    const float* xb  = x + b * TLEN * CDIM;
    const int wid = tid >> 6;

    #pragma unroll
    for (int rp = 0; rp < 2; ++rp) {
        const int i   = rp ? iB : iA;
        const int row = b * TLEN + i;
        const int j   = tid;

        float s = -1e30f;
        if (j <= i) {
            const float* hb = hkb + j;        // + c*TLEN per step, coalesced
            float a0 = 0.f, a1 = 0.f, a2 = 0.f, a3 = 0.f;
            #pragma unroll
            for (int c = 0; c < CDIM; c += 4) {
                const float k0 = hb[(c + 0) * TLEN];
                const float k1 = hb[(c + 1) * TLEN];
                const float k2 = hb[(c + 2) * TLEN];
                const float k3 = hb[(c + 3) * TLEN];
                a0 = fmaf(fmaxf(k0 + hq_s[rp][c + 0], 0.f), w2_s[c + 0], a0);
                a1 = fmaf(fmaxf(k1 + hq_s[rp][c + 1], 0.f), w2_s[c + 1], a1);
                a2 = fmaf(fmaxf(k2 + hq_s[rp][c + 2], 0.f), w2_s[c + 2], a2);
                a3 = fmaf(fmaxf(k3 + hq_s[rp][c + 3], 0.f), w2_s[c + 3], a3);
            }
            s = ((a0 + a1) + (a2 + a3) + b2v) * 0.125f;
        }

        // block max
        float m_local = s;
        #pragma unroll
        for (int off = 32; off > 0; off >>= 1)
            m_local = fmaxf(m_local, __shfl_xor(m_local, off));
        if ((tid & 63) == 0) red_s[wid] = m_local;
        __syncthreads();
        float m = red_s[0];
        #pragma unroll
        for (int w = 1; w < 8; ++w) m = fmaxf(m, red_s[w]);

        const float p = (j <= i) ? __expf(s - m) : 0.f;
        p_s[j] = p;
        float sum_local = p;
        #pragma unroll
        for (int off = 32; off > 0; off >>= 1)
            sum_local += __shfl_xor(sum_local, off);
        __syncthreads();                       // max consumed; p_s visible
        if ((tid & 63) == 0) red_s[wid] = sum_local;
        __syncthreads();
        float sum = red_s[0];
        #pragma unroll
        for (int w = 1; w < 8; ++w) sum += red_s[w];
        const float inv = 1.f / sum;

        // o = sum_j p_j * x_j  (8 j-groups, float4 p reads, coalesced x rows)
        const int h = tid & 63;
        const int g = wid;
        const float* xh = xb + h;
        const float4* p4 = (const float4*)p_s;
        const int nj4 = (i >> 2) + 1;
        float a0 = 0.f, a1 = 0.f, a2 = 0.f, a3 = 0.f;
        for (int j4 = g; j4 < nj4; j4 += 8) {
            const float4 pp = p4[j4];
            const int j0 = j4 * 4;
            a0 = fmaf(pp.x, xh[j0 * CDIM],       a0);
            a1 = fmaf(pp.y, xh[(j0 + 1) * CDIM], a1);
            a2 = fmaf(pp.z, xh[(j0 + 2) * CDIM], a2);
            a3 = fmaf(pp.w, xh[(j0 + 3) * CDIM], a3);
        }
        pv_s[g][h] = (a0 + a1) + (a2 + a3);
        __syncthreads();
        if (tid < CDIM) {
            float o = pv_s[0][tid];
            #pragma unroll
            for (int w = 1; w < 8; ++w) o += pv_s[w][tid];
            o_s[tid] = o;
        }
        __syncthreads();
        if (tid < CDIM) {                      // out[h] = (o . Wv[h,:]) * inv
            const float4* wv = (const float4*)(Wv + tid * CDIM);
            const float4* o4 = (const float4*)o_s;
            float4 a = make_float4(0.f, 0.f, 0.f, 0.f);
            #pragma unroll
            for (int c4 = 0; c4 < 16; ++c4) {
                const float4 ww = wv[c4];
                const float4 oo = o4[c4];
                a.x = fmaf(oo.x, ww.x, a.x); a.y = fmaf(oo.y, ww.y, a.y);
                a.z = fmaf(oo.z, ww.z, a.z); a.w = fmaf(oo.w, ww.w, a.w);
            }
            out[row * CDIM + tid] = ((a.x + a.y) + (a.z + a.w)) * inv;
        }
        __syncthreads();                       // protect shared bufs for rp=1
    }
}

extern "C" void kernel_launch(void* const* d_in, const int* in_sizes, int n_in,
                              void* d_out, int out_size, void* d_ws, size_t ws_size,
                              hipStream_t stream)
{
    const float* x   = (const float*)d_in[0];
    const float* pos = (const float*)d_in[1];
    const float* W1  = (const float*)d_in[2];
    const float* b1  = (const float*)d_in[3];
    const float* W2  = (const float*)d_in[4];
    const float* b2  = (const float*)d_in[5];
    const float* Wv  = (const float*)d_in[6];
    float* out = (float*)d_out;

    float* hkt = (float*)d_ws;                // 256 KiB scratch, [b][c][t]

    hk_kernel<<<BDIM * TLEN / 4, 256, 0, stream>>>(x, pos, W1, hkt);
    attn_kernel<<<BDIM * TLEN / 2, 512, 0, stream>>>(x, pos, W1, b1, W2, b2, Wv,
                                                     hkt, out);
}